// Round 2
// baseline (241.644 us; speedup 1.0000x reference)
//
#include <hip/hip_runtime.h>

// ScRRAMBLe capsule layer — R5: FUSED single kernel.
//   xr[k,m] = sum_ij Ci[ij, c, k] * x[ij, m]          (route, per capsule c)
//   y[c,j,l] = sum_{k,m} Wi[c,j,k,l,m] * xr[k,m]      (transform)
//
// R4 counters: top-5 dispatches are ALL 512MiB workspace poison fills
// (~79us @ 6.8TB/s, harness-side, fixed). Our kernels are each <78us but
// together + launches hold ~140us vs a ~25us floor. Fusion deletes the
// xr_part HBM round-trip and one launch; 512MiB poison > 256MiB L3 means
// Wi re-streams from HBM every iter (21us floor) regardless -> plain
// coalesced loads, double-buffered, group 0 prefetched under route VALU.
//
// Layout: block = capsule c (512 blocks, 256 thr, 4 waves).
//   Phase 1 (route): wave w owns ij in [w*512, w*512+512); lane = m (0..63).
//     Ci4[ij*512+c] is wave-uniform (1 tx broadcast); x[ij*64+m] is 256B
//     coalesced. acc(f4) = xr[0..3][m] partial. 4KB LDS reduce across waves.
//   Phase 2 (transform): wave w = j. Per thread (lq=lane>>4, m16=lane&15):
//     Wi f4 loads 64-lane contiguous (1KB/instr), 16-deep x2 double buffer.

typedef float f4 __attribute__((ext_vector_type(4)));

__global__ __launch_bounds__(256, 2) void fused_caps_kernel(
    const float* __restrict__ x,
    const float* __restrict__ Ci,
    const float* __restrict__ Wi,
    float* __restrict__ y)
{
    const int c    = blockIdx.x;
    const int t    = threadIdx.x;
    const int w    = t >> 6;          // phase1: ij subgroup; phase2: j
    const int lane = t & 63;
    const int lq   = lane >> 4;
    const int m16  = lane & 15;

    const f4* __restrict__ Ci4 = (const f4*)Ci;
    const f4* __restrict__ W4  = (const f4*)Wi;

    __shared__ float part[4 * 4 * 64];   // [sg][k][m]

    const int wbase = ((c << 2) + w) << 12;   // (c*4 + w) * 4096 f4

    f4 wvA[16], wvB[16];

#define PREFETCH(dst, g4)                                                   \
    _Pragma("unroll")                                                       \
    for (int c2 = 0; c2 < 4; ++c2) {                                        \
        const int l = ((g4) << 4) + (c2 << 2) + lq;                         \
        _Pragma("unroll")                                                   \
        for (int k = 0; k < 4; ++k)                                         \
            dst[(c2 << 2) + k] = W4[wbase + (k << 10) + l * 16 + m16];      \
    }

#define COMPUTE(src, g4)                                                    \
    _Pragma("unroll")                                                       \
    for (int c2 = 0; c2 < 4; ++c2) {                                        \
        f4 s = src[(c2 << 2) + 0] * xr0 + src[(c2 << 2) + 1] * xr1          \
             + src[(c2 << 2) + 2] * xr2 + src[(c2 << 2) + 3] * xr3;         \
        float p = s.x + s.y + s.z + s.w;                                    \
        p += __shfl_xor(p, 1);                                              \
        p += __shfl_xor(p, 2);                                              \
        p += __shfl_xor(p, 4);                                              \
        p += __shfl_xor(p, 8);                                              \
        if (m16 == 0)                                                       \
            y[(((c << 2) + w) << 6) + ((g4) << 4) + (c2 << 2) + lq] = p;    \
    }

    // Wi group 0 issued first: latency hides under route's ~4k VALU cycles.
    PREFETCH(wvA, 0)

    // ---- Phase 1: route ----
    f4 acc = {0.f, 0.f, 0.f, 0.f};
    {
        const int ij0 = w << 9;
        const float* __restrict__ xp = x + lane;
        #pragma unroll 8
        for (int it = 0; it < 512; ++it) {
            const int ij   = ij0 + it;
            const f4 cv    = Ci4[ij * 512 + c];   // wave-uniform broadcast
            const float xv = xp[ij << 6];         // 256B coalesced per wave
            acc += cv * xv;
        }
    }
    part[(w << 8) +   0 + lane] = acc.x;
    part[(w << 8) +  64 + lane] = acc.y;
    part[(w << 8) + 128 + lane] = acc.z;
    part[(w << 8) + 192 + lane] = acc.w;
    __syncthreads();
    // (compiler drains vmcnt at the barrier -> wvA complete here anyway)

    // Cross-wave reduce: xr[k] as f4 over this lane's m16 quad.
    const f4* partf4 = (const f4*)part;
    f4 xr0 = partf4[  0 + m16] + partf4[ 64 + m16] + partf4[128 + m16] + partf4[192 + m16];
    f4 xr1 = partf4[ 16 + m16] + partf4[ 80 + m16] + partf4[144 + m16] + partf4[208 + m16];
    f4 xr2 = partf4[ 32 + m16] + partf4[ 96 + m16] + partf4[160 + m16] + partf4[224 + m16];
    f4 xr3 = partf4[ 48 + m16] + partf4[112 + m16] + partf4[176 + m16] + partf4[240 + m16];

    // ---- Phase 2: transform, 2-deep double buffer ----
    PREFETCH(wvB, 1)
    COMPUTE(wvA, 0)
    PREFETCH(wvA, 2)
    COMPUTE(wvB, 1)
    PREFETCH(wvB, 3)
    COMPUTE(wvA, 2)
    COMPUTE(wvB, 3)

#undef PREFETCH
#undef COMPUTE
}

extern "C" void kernel_launch(void* const* d_in, const int* in_sizes, int n_in,
                              void* d_out, int out_size, void* d_ws, size_t ws_size,
                              hipStream_t stream) {
    const float* x  = (const float*)d_in[0];   // 131072 floats
    const float* Ci = (const float*)d_in[1];   // 2048 * 512 * 4 floats (16 MB)
    const float* Wi = (const float*)d_in[2];   // 512*4*4*64*64 floats (134 MB)
    float* y = (float*)d_out;                  // 512*4*64 floats

    fused_caps_kernel<<<512, 256, 0, stream>>>(x, Ci, Wi, y);
}

// Round 4
// 240.992 us; speedup vs baseline: 1.0027x; 1.0027x over previous
//
#include <hip/hip_runtime.h>

// ScRRAMBLe capsule layer — R6: fused kernel, route MLP fixed.
//   xr[k,m] = sum_ij Ci[ij, c, k] * x[ij, m]          (route, per capsule c)
//   y[c,j,l] = sum_{k,m} Wi[c,j,k,l,m] * xr[k,m]      (transform)
//
// R5 post-mortem: fused kernel 98us @ 1.4TB/s, VALUBusy 9% -> latency-bound.
// VGPR=92: the cross-phase wvA[16] prefetch (64 VGPR) strangled the route
// loop's unrolling -> ~2 loads in flight, 512 cold wave-uniform Ci gathers
// at ~900cy each ~= 77us. R6: (a) drop cross-phase prefetch (phase 2 is
// chip-wide BW-bound anyway, 8 streaming waves/CU cover latency), (b) route
// hand-batched 16-deep (32 loads in flight, ~100 VGPR now available),
// (c) phase 2 issues both buffers before first compute.
// Predicted: kernel ~30-38us, FETCH_SIZE unchanged ~133MB, hbm ~4+TB/s.
// R7: infra failure (no bench/counters) -> byte-identical resubmit.
//
// Layout: block = capsule c (512 blocks, 256 thr, 4 waves, 2 blocks/CU).
//   Phase 1: wave w owns ij in [w*512, w*512+512); lane = m.
//     Ci4[ij*512+c] wave-uniform broadcast; x[ij*64+lane] 256B coalesced.
//   Phase 2: wave w = j; (lq=lane>>4, m16=lane&15); Wi f4 loads 1KB/instr.

typedef float f4 __attribute__((ext_vector_type(4)));

__global__ __launch_bounds__(256, 2) void fused_caps_kernel(
    const float* __restrict__ x,
    const float* __restrict__ Ci,
    const float* __restrict__ Wi,
    float* __restrict__ y)
{
    const int c    = blockIdx.x;
    const int t    = threadIdx.x;
    const int w    = t >> 6;          // phase1: ij subgroup; phase2: j
    const int lane = t & 63;
    const int lq   = lane >> 4;
    const int m16  = lane & 15;

    const f4* __restrict__ Ci4 = (const f4*)Ci;
    const f4* __restrict__ W4  = (const f4*)Wi;

    __shared__ float part[4 * 4 * 64];   // [sg][k][m]

    // ---- Phase 1: route, 16-deep load batches -> 32 loads in flight ----
    f4 acc = {0.f, 0.f, 0.f, 0.f};
    {
        const int ij0 = w << 9;
        for (int it = 0; it < 512; it += 16) {
            f4 cv[16];
            float xv[16];
            #pragma unroll
            for (int u = 0; u < 16; ++u) {
                const int ij = ij0 + it + u;
                cv[u] = Ci4[ij * 512 + c];      // wave-uniform broadcast
                xv[u] = x[(ij << 6) + lane];    // 256B coalesced per wave
            }
            #pragma unroll
            for (int u = 0; u < 16; ++u)
                acc += cv[u] * xv[u];
        }
    }
    part[(w << 8) +   0 + lane] = acc.x;
    part[(w << 8) +  64 + lane] = acc.y;
    part[(w << 8) + 128 + lane] = acc.z;
    part[(w << 8) + 192 + lane] = acc.w;
    __syncthreads();

    // Cross-wave reduce: xr[k] as f4 over this lane's m16 quad.
    // (lq groups read identical addresses -> LDS broadcast, conflict-free)
    const f4* partf4 = (const f4*)part;
    f4 xr0 = partf4[  0 + m16] + partf4[ 64 + m16] + partf4[128 + m16] + partf4[192 + m16];
    f4 xr1 = partf4[ 16 + m16] + partf4[ 80 + m16] + partf4[144 + m16] + partf4[208 + m16];
    f4 xr2 = partf4[ 32 + m16] + partf4[ 96 + m16] + partf4[160 + m16] + partf4[224 + m16];
    f4 xr3 = partf4[ 48 + m16] + partf4[112 + m16] + partf4[176 + m16] + partf4[240 + m16];

    // ---- Phase 2: transform, 2-deep double buffer ----
    const int wbase = ((c << 2) + w) << 12;   // (c*4 + w) * 4096 f4

    f4 wvA[16], wvB[16];

#define PREFETCH(dst, g4)                                                   \
    _Pragma("unroll")                                                       \
    for (int c2 = 0; c2 < 4; ++c2) {                                        \
        const int l = ((g4) << 4) + (c2 << 2) + lq;                         \
        _Pragma("unroll")                                                   \
        for (int k = 0; k < 4; ++k)                                         \
            dst[(c2 << 2) + k] = W4[wbase + (k << 10) + l * 16 + m16];      \
    }

#define COMPUTE(src, g4)                                                    \
    _Pragma("unroll")                                                       \
    for (int c2 = 0; c2 < 4; ++c2) {                                        \
        f4 s = src[(c2 << 2) + 0] * xr0 + src[(c2 << 2) + 1] * xr1          \
             + src[(c2 << 2) + 2] * xr2 + src[(c2 << 2) + 3] * xr3;         \
        float p = s.x + s.y + s.z + s.w;                                    \
        p += __shfl_xor(p, 1);                                              \
        p += __shfl_xor(p, 2);                                              \
        p += __shfl_xor(p, 4);                                              \
        p += __shfl_xor(p, 8);                                              \
        if (m16 == 0)                                                       \
            y[(((c << 2) + w) << 6) + ((g4) << 4) + (c2 << 2) + lq] = p;    \
    }

    PREFETCH(wvA, 0)
    PREFETCH(wvB, 1)
    COMPUTE(wvA, 0)
    PREFETCH(wvA, 2)
    COMPUTE(wvB, 1)
    PREFETCH(wvB, 3)
    COMPUTE(wvA, 2)
    COMPUTE(wvB, 3)

#undef PREFETCH
#undef COMPUTE
}

extern "C" void kernel_launch(void* const* d_in, const int* in_sizes, int n_in,
                              void* d_out, int out_size, void* d_ws, size_t ws_size,
                              hipStream_t stream) {
    const float* x  = (const float*)d_in[0];   // 131072 floats
    const float* Ci = (const float*)d_in[1];   // 2048 * 512 * 4 floats (16 MB)
    const float* Wi = (const float*)d_in[2];   // 512*4*4*64*64 floats (134 MB)
    float* y = (float*)d_out;                  // 512*4*64 floats

    fused_caps_kernel<<<512, 256, 0, stream>>>(x, Ci, Wi, y);
}

// Round 5
// 224.499 us; speedup vs baseline: 1.0764x; 1.0735x over previous
//
#include <hip/hip_runtime.h>

// ScRRAMBLe capsule layer — R8: fused kernel, Ci staged to LDS.
//   xr[k,m] = sum_ij Ci[ij, c, k] * x[ij, m]          (route, per capsule c)
//   y[c,j,l] = sum_{k,m} Wi[c,j,k,l,m] * xr[k,m]      (transform)
//
// R6 post-mortem: 16-deep route batch REFUSED by regalloc (cv[16]=64 VGPR;
// compiler held VGPR=88 and re-interleaved loads w/ FMAs -> MLP ~2.5, route
// ~77us of the 97us kernel). R8 fix: fetch Ci with LANE-parallelism, not
// register depth: stage the 32KB Ci column via 8 gathers/thread (64 lanes
// x 16B independent lines per instr ~= 512 fetches in flight per block),
// then route reads Ci from LDS (uniform broadcast, conflict-free). x loads
// (1 VGPR each, L2-resident) batch 16-deep for cheap. Phase 2 unchanged:
// 8 waves/CU x ~8x1KB in flight >> BW-delay product -> HBM-bound ~21us.
// Predicted: kernel ~28-35us, hbm ~4-5TB/s, VALUBusy ~30%, total ~170us.
//
// Layout: block = capsule c (512 blocks, 256 thr, 4 waves, 2 blocks/CU).
//   Stage: thread t loads Ci4[(t+256u)*512+c], u=0..7 -> ci_s[t+256u].
//   Phase 1: wave w owns ij in [w*512, w*512+512); lane = m.
//   Phase 2: wave w = j; (lq=lane>>4, m16=lane&15); Wi f4 loads 1KB/instr.

typedef float f4 __attribute__((ext_vector_type(4)));

__global__ __launch_bounds__(256, 2) void fused_caps_kernel(
    const float* __restrict__ x,
    const float* __restrict__ Ci,
    const float* __restrict__ Wi,
    float* __restrict__ y)
{
    const int c    = blockIdx.x;
    const int t    = threadIdx.x;
    const int w    = t >> 6;          // phase1: ij subgroup; phase2: j
    const int lane = t & 63;
    const int lq   = lane >> 4;
    const int m16  = lane & 15;

    const f4* __restrict__ Ci4 = (const f4*)Ci;
    const f4* __restrict__ W4  = (const f4*)Wi;

    __shared__ f4    ci_s[2048];         // 32 KB: Ci[:, c, 0:4]
    __shared__ float part[4 * 4 * 64];   // 4 KB: [sg][k][m]

    // ---- Stage Ci column -> LDS: 8 lane-parallel gathers per thread ----
    {
        f4 cv[8];
        #pragma unroll
        for (int u = 0; u < 8; ++u)
            cv[u] = Ci4[(t + (u << 8)) * 512 + c];   // 64 distinct lines/instr
        #pragma unroll
        for (int u = 0; u < 8; ++u)
            ci_s[t + (u << 8)] = cv[u];              // consecutive-f4 write
    }
    __syncthreads();

    // ---- Phase 1: route; wave w owns ij in [w*512, w*512+512) ----
    f4 acc = {0.f, 0.f, 0.f, 0.f};
    {
        const int ij0 = w << 9;
        const float* __restrict__ xp = x + lane;
        for (int it = 0; it < 512; it += 16) {
            float xv[16];
            #pragma unroll
            for (int u = 0; u < 16; ++u)
                xv[u] = xp[(ij0 + it + u) << 6];     // 256B coalesced, L2-res
            #pragma unroll
            for (int u = 0; u < 16; ++u)
                acc += ci_s[ij0 + it + u] * xv[u];   // LDS broadcast read
        }
    }
    part[(w << 8) +   0 + lane] = acc.x;
    part[(w << 8) +  64 + lane] = acc.y;
    part[(w << 8) + 128 + lane] = acc.z;
    part[(w << 8) + 192 + lane] = acc.w;
    __syncthreads();

    // Cross-wave reduce: xr[k] as f4 over this lane's m16 quad.
    // (lq groups read identical addresses -> LDS broadcast, conflict-free)
    const f4* partf4 = (const f4*)part;
    f4 xr0 = partf4[  0 + m16] + partf4[ 64 + m16] + partf4[128 + m16] + partf4[192 + m16];
    f4 xr1 = partf4[ 16 + m16] + partf4[ 80 + m16] + partf4[144 + m16] + partf4[208 + m16];
    f4 xr2 = partf4[ 32 + m16] + partf4[ 96 + m16] + partf4[160 + m16] + partf4[224 + m16];
    f4 xr3 = partf4[ 48 + m16] + partf4[112 + m16] + partf4[176 + m16] + partf4[240 + m16];

    // ---- Phase 2: transform, 2-deep double buffer (unchanged from R6) ----
    const int wbase = ((c << 2) + w) << 12;   // (c*4 + w) * 4096 f4

    f4 wvA[16], wvB[16];

#define PREFETCH(dst, g4)                                                   \
    _Pragma("unroll")                                                       \
    for (int c2 = 0; c2 < 4; ++c2) {                                        \
        const int l = ((g4) << 4) + (c2 << 2) + lq;                         \
        _Pragma("unroll")                                                   \
        for (int k = 0; k < 4; ++k)                                         \
            dst[(c2 << 2) + k] =                                            \
                __builtin_nontemporal_load(&W4[wbase + (k << 10) + l * 16 + m16]); \
    }

#define COMPUTE(src, g4)                                                    \
    _Pragma("unroll")                                                       \
    for (int c2 = 0; c2 < 4; ++c2) {                                        \
        f4 s = src[(c2 << 2) + 0] * xr0 + src[(c2 << 2) + 1] * xr1          \
             + src[(c2 << 2) + 2] * xr2 + src[(c2 << 2) + 3] * xr3;         \
        float p = s.x + s.y + s.z + s.w;                                    \
        p += __shfl_xor(p, 1);                                              \
        p += __shfl_xor(p, 2);                                              \
        p += __shfl_xor(p, 4);                                              \
        p += __shfl_xor(p, 8);                                              \
        if (m16 == 0)                                                       \
            y[(((c << 2) + w) << 6) + ((g4) << 4) + (c2 << 2) + lq] = p;    \
    }

    PREFETCH(wvA, 0)
    PREFETCH(wvB, 1)
    COMPUTE(wvA, 0)
    PREFETCH(wvA, 2)
    COMPUTE(wvB, 1)
    PREFETCH(wvB, 3)
    COMPUTE(wvA, 2)
    COMPUTE(wvB, 3)

#undef PREFETCH
#undef COMPUTE
}

extern "C" void kernel_launch(void* const* d_in, const int* in_sizes, int n_in,
                              void* d_out, int out_size, void* d_ws, size_t ws_size,
                              hipStream_t stream) {
    const float* x  = (const float*)d_in[0];   // 131072 floats
    const float* Ci = (const float*)d_in[1];   // 2048 * 512 * 4 floats (16 MB)
    const float* Wi = (const float*)d_in[2];   // 512*4*4*64*64 floats (134 MB)
    float* y = (float*)d_out;                  // 512*4*64 floats

    fused_caps_kernel<<<512, 256, 0, stream>>>(x, Ci, Wi, y);
}